// Round 6
// baseline (185.279 us; speedup 1.0000x reference)
//
#include <hip/hip_runtime.h>

// MACD: EMA_slow(x) - EMA_fast(x) over time axis.
// x: [B=4096, T=2048, F=8] fp32 contiguous.
// Persistent double-buffered pipeline: grid = 256 (1 block/CU), each block
// processes B/256 rows. While computing row r from buf[cur], row r+256's
// loads are in flight (reg-staged, T14 split). All global traffic is
// lane-contiguous float4; LDS XOR-swizzled for conflict-free chunk reads.
// Raw s_barrier + lgkmcnt(0) only (no vmcnt drain -> prefetch survives).

#define T_LEN 2048
#define FDIM  8
#define CHUNK 4
#define NTHR  512                 // == NCHUNK = T_LEN/CHUNK
#define NWAVE (NTHR / 64)
#define NF4   (T_LEN * FDIM / 4)  // 4096 float4 slots per row
#define LD_PT (NF4 / NTHR)        // 8 float4 per thread for stage/copyout
#define GRID  256

__device__ __forceinline__ int swz(int g) { return g ^ ((g >> 4) & 7); }

// LDS-fence barrier WITHOUT vmcnt drain (keeps global prefetch in flight).
__device__ __forceinline__ void ldsbar() {
    asm volatile("s_waitcnt lgkmcnt(0)" ::: "memory");
    __builtin_amdgcn_s_barrier();
}

__global__ __launch_bounds__(NTHR, 2)
void macd_kernel(const float* __restrict__ x, float* __restrict__ out, int B) {
    const float AS  = 2.0f / 27.0f;          // alpha slow (N=26)
    const float AF  = 2.0f / 13.0f;          // alpha fast (N=12)
    const float OMS = 1.0f - AS;
    const float OMF = 1.0f - AF;
    const float DS  = (OMS*OMS)*(OMS*OMS);   // per-chunk decay OMS^4
    const float DF  = (OMF*OMF)*(OMF*OMF);

    __shared__ float4 buf[2][NF4];           // 128 KiB -> 1 block/CU
    __shared__ float  W[NWAVE][16];

    const int j = threadIdx.x;
    const int w = j >> 6, l = j & 63;
    const int c = j;                         // chunk id
    const int base = 8 * c;                  // first slot of chunk
    const int key  = (c >> 1) & 7;           // swz key (slots 8c..8c+7)

    // per-lane D^l (binary powering, const bases)
    float Dls = 1.f, Dlf = 1.f;
    {
        float ms2 = DS, mf2 = DF;
#pragma unroll
        for (int bit = 0; bit < 6; ++bit) {
            if ((l >> bit) & 1) { Dls *= ms2; Dlf *= mf2; }
            ms2 *= ms2; mf2 *= mf2;
        }
    }

    int r = blockIdx.x;
    if (r >= B) return;

    // ---- prologue: stage first row into buf[0] ----------------------------
    {
        const float4* xg = (const float4*)(x + (size_t)r * (T_LEN * FDIM));
#pragma unroll
        for (int k = 0; k < LD_PT; ++k) {
            int g = k * NTHR + j;
            buf[0][swz(g)] = xg[g];
        }
        ldsbar();
    }

    int cur = 0;
    for (; r < B; r += GRID, cur ^= 1) {
        // ---- issue next row's loads early (prefetch into regs) ------------
        const int rn = r + GRID;
        const bool pf = (rn < B);
        float4 nx[LD_PT];
        if (pf) {
            const float4* xg = (const float4*)(x + (size_t)rn * (T_LEN * FDIM));
#pragma unroll
            for (int k = 0; k < LD_PT; ++k) nx[k] = xg[k * NTHR + j];
        }

        // ---- phase 1: per-chunk zero-init EMA partials --------------------
        float p[16];                         // p[2f]=slow, p[2f+1]=fast
#pragma unroll
        for (int s = 0; s < 16; ++s) p[s] = 0.f;
#pragma unroll
        for (int t = 0; t < CHUNK; ++t) {
            float4 lo = buf[cur][(base + 2*t    ) ^ key];
            float4 hi = buf[cur][(base + 2*t + 1) ^ key];
            float xx[8] = {lo.x,lo.y,lo.z,lo.w, hi.x,hi.y,hi.z,hi.w};
#pragma unroll
            for (int f = 0; f < 8; ++f) {
                p[2*f+0] = AS * xx[f] + OMS * p[2*f+0];
                p[2*f+1] = AF * xx[f] + OMF * p[2*f+1];
            }
        }
        // seed y_{-1} = x0 into chunk 0 (exact y0 = x0 chain)
        const float* xs = (const float*)&buf[cur][0];   // slots 0,1 swz=id
        if (j == 0) {
#pragma unroll
            for (int f = 0; f < 8; ++f) {
                float x0 = xs[f];
                p[2*f+0] += DS * x0;
                p[2*f+1] += DF * x0;
            }
        }

        // ---- intra-wave Kogge-Stone (no barriers) -------------------------
        float Ms = DS, Mf = DF;
#pragma unroll
        for (int off = 1; off < 64; off <<= 1) {
#pragma unroll
            for (int s = 0; s < 16; ++s) {
                float tv = __shfl_up(p[s], (unsigned)off, 64);
                if (l >= off) p[s] += ((s & 1) ? Mf : Ms) * tv;
            }
            Ms *= Ms; Mf *= Mf;              // ends as D^64 (per-wave decay)
        }
        float qe[16];
#pragma unroll
        for (int s = 0; s < 16; ++s) qe[s] = __shfl_up(p[s], 1u, 64);

        // ---- cross-wave combine -------------------------------------------
        if (l == 63) {
#pragma unroll
            for (int s = 0; s < 16; ++s) W[w][s] = p[s];
        }
        ldsbar();
        float Sp[16];
#pragma unroll
        for (int s = 0; s < 16; ++s) Sp[s] = 0.f;
        for (int v = 0; v < w; ++v) {        // <=7 iters, wave-uniform
#pragma unroll
            for (int s = 0; s < 16; ++s)
                Sp[s] = W[v][s] + ((s & 1) ? Mf : Ms) * Sp[s];
        }

        // ---- carry-in, phase 2 (in-place output) --------------------------
        float ys[8], yf[8];
#pragma unroll
        for (int f = 0; f < 8; ++f) {
            ys[f] = (l == 0) ? Sp[2*f+0] : qe[2*f+0] + Dls * Sp[2*f+0];
            yf[f] = (l == 0) ? Sp[2*f+1] : qe[2*f+1] + Dlf * Sp[2*f+1];
        }
        if (j == 0) {
#pragma unroll
            for (int f = 0; f < 8; ++f) { ys[f] = xs[f]; yf[f] = xs[f]; }
        }
#pragma unroll
        for (int t = 0; t < CHUNK; ++t) {
            int slo = (base + 2*t    ) ^ key;
            int shi = (base + 2*t + 1) ^ key;
            float4 lo = buf[cur][slo];
            float4 hi = buf[cur][shi];
            float xx[8] = {lo.x,lo.y,lo.z,lo.w, hi.x,hi.y,hi.z,hi.w};
            float o[8];
#pragma unroll
            for (int f = 0; f < 8; ++f) {
                ys[f] = AS * xx[f] + OMS * ys[f];
                yf[f] = AF * xx[f] + OMF * yf[f];
                o[f]  = ys[f] - yf[f];
            }
            buf[cur][slo] = make_float4(o[0], o[1], o[2], o[3]);
            buf[cur][shi] = make_float4(o[4], o[5], o[6], o[7]);
        }
        ldsbar();                            // outputs visible block-wide

        // ---- copyout row r (coalesced), then stage next row ---------------
        float4* og = (float4*)(out + (size_t)r * (T_LEN * FDIM));
#pragma unroll
        for (int k = 0; k < LD_PT; ++k) {
            int g = k * NTHR + j;
            og[g] = buf[cur][swz(g)];
        }
        if (pf) {
#pragma unroll
            for (int k = 0; k < LD_PT; ++k)
                buf[cur ^ 1][swz(k * NTHR + j)] = nx[k];
        }
        ldsbar();   // closes copyout reads + staging writes for next iter
    }
}

extern "C" void kernel_launch(void* const* d_in, const int* in_sizes, int n_in,
                              void* d_out, int out_size, void* d_ws, size_t ws_size,
                              hipStream_t stream) {
    (void)n_in; (void)d_ws; (void)ws_size; (void)out_size;
    const float* x = (const float*)d_in[0];
    float* out = (float*)d_out;
    const int B = in_sizes[0] / (T_LEN * FDIM);   // 4096
    const int grid = (B < GRID) ? B : GRID;
    macd_kernel<<<dim3(grid), dim3(NTHR), 0, stream>>>(x, out, B);
}

// Round 8
// 89.731 us; speedup vs baseline: 2.0648x; 2.0648x over previous
//
#include <hip/hip_runtime.h>

// MACD: EMA_slow(x) - EMA_fast(x) over time axis.
// x: [B=4096, T=2048, F=8] fp32 contiguous. Block per row b (256 threads),
// row processed as TWO sequential 32 KB half-row tiles (carry chained via
// LDS handoff) -> 4 blocks/CU for phase overlap. All global traffic is
// lane-contiguous float4; LDS XOR-swizzled for conflict-free b128 access.

#define T_LEN  2048
#define FDIM   8
#define NTHR   256
#define TILE_T 1024
#define NTILE  (T_LEN / TILE_T)        // 2
#define CHUNK  (TILE_T / NTHR)         // 4 timesteps per thread
#define NF4_T  (TILE_T * FDIM / 4)     // 2048 float4 slots per tile
#define LD_PT  (NF4_T / NTHR)          // 8 float4 per thread stage/copyout
#define NWAVE  (NTHR / 64)

typedef float f32x4 __attribute__((ext_vector_type(4)));   // native vec4

// involution on float4-slot index: flips bits 0-2 keyed on bits 4-6.
__device__ __forceinline__ int swz(int g) { return g ^ ((g >> 4) & 7); }

__global__ __launch_bounds__(NTHR, 4)
void macd_kernel(const float* __restrict__ x, float* __restrict__ out) {
    const float AS  = 2.0f / 27.0f;    // alpha slow (N=26)
    const float AF  = 2.0f / 13.0f;    // alpha fast (N=12)
    const float OMS = 1.0f - AS;
    const float OMF = 1.0f - AF;
    const float DS  = (OMS*OMS)*(OMS*OMS);   // per-chunk decay OMS^CHUNK
    const float DF  = (OMF*OMF)*(OMF*OMF);

    __shared__ float4 buf[NF4_T];      // 32 KiB half-row tile (swizzled)
    __shared__ float  W[NWAVE][16];    // wave-total partials
    __shared__ float  carryS[FDIM], carryF[FDIM];   // tile->tile handoff

    const int b = blockIdx.x;
    const int j = threadIdx.x;         // chunk id within tile, 0..255
    const int w = j >> 6, l = j & 63;
    const int base = LD_PT * j;        // first slot of chunk (8j)
    const int key  = (j >> 1) & 7;     // swz key for slots 8j..8j+7

    // per-lane D^l via binary powering (exact multiplies)
    float Dls = 1.f, Dlf = 1.f;
    {
        float ms2 = DS, mf2 = DF;
#pragma unroll
        for (int bit = 0; bit < 6; ++bit) {
            if ((l >> bit) & 1) { Dls *= ms2; Dlf *= mf2; }
            ms2 *= ms2; mf2 *= mf2;
        }
    }

    const float* xrow = x   + (size_t)b * (T_LEN * FDIM);
    float*       orow = out + (size_t)b * (T_LEN * FDIM);

    for (int tile = 0; tile < NTILE; ++tile) {
        const float4* xg = (const float4*)(xrow + tile * (TILE_T * FDIM));
        f32x4*        og = (f32x4*)(orow + tile * (TILE_T * FDIM));

        if (tile) __syncthreads();     // prev copyout reads done before overwrite

        // ---- stage: coalesced float4 reads -> swizzled LDS ----------------
#pragma unroll
        for (int k = 0; k < LD_PT; ++k) {
            int g = k * NTHR + j;
            buf[swz(g)] = xg[g];
        }
        __syncthreads();

        // ---- carry-in for this tile (broadcast) ---------------------------
        float cin_s[FDIM], cin_f[FDIM];
        if (tile == 0) {
            const float* xs = (const float*)&buf[0];   // slots 0,1: swz = id
#pragma unroll
            for (int f = 0; f < FDIM; ++f) { cin_s[f] = xs[f]; cin_f[f] = xs[f]; }
        } else {
#pragma unroll
            for (int f = 0; f < FDIM; ++f) { cin_s[f] = carryS[f]; cin_f[f] = carryF[f]; }
        }

        // ---- phase 1: per-chunk zero-init EMA partials --------------------
        float p[16];                   // p[2f]=slow, p[2f+1]=fast
#pragma unroll
        for (int s = 0; s < 16; ++s) p[s] = 0.f;
#pragma unroll
        for (int t = 0; t < CHUNK; ++t) {
            float4 lo = buf[(base + 2*t    ) ^ key];
            float4 hi = buf[(base + 2*t + 1) ^ key];
            float xx[8] = {lo.x,lo.y,lo.z,lo.w, hi.x,hi.y,hi.z,hi.w};
#pragma unroll
            for (int f = 0; f < 8; ++f) {
                p[2*f+0] = AS * xx[f] + OMS * p[2*f+0];
                p[2*f+1] = AF * xx[f] + OMF * p[2*f+1];
            }
        }
        // fold carry into chunk 0's partial (exact recurrence seed)
        if (j == 0) {
#pragma unroll
            for (int f = 0; f < 8; ++f) {
                p[2*f+0] += DS * cin_s[f];
                p[2*f+1] += DF * cin_f[f];
            }
        }

        // ---- intra-wave inclusive Kogge-Stone scan (no barriers) ----------
        float Ms = DS, Mf = DF;
#pragma unroll
        for (int off = 1; off < 64; off <<= 1) {
#pragma unroll
            for (int s = 0; s < 16; ++s) {
                float tv = __shfl_up(p[s], (unsigned)off, 64);
                if (l >= off) p[s] += ((s & 1) ? Mf : Ms) * tv;
            }
            Ms *= Ms; Mf *= Mf;        // ends as D^64 (per-wave decay)
        }
        float qe[16];                  // exclusive-within-wave (lane l-1)
#pragma unroll
        for (int s = 0; s < 16; ++s) qe[s] = __shfl_up(p[s], 1u, 64);

        // ---- cross-wave combine (1 barrier) -------------------------------
        if (l == 63) {
#pragma unroll
            for (int s = 0; s < 16; ++s) W[w][s] = p[s];
        }
        __syncthreads();
        float Sp[16];                  // block scan at end of wave w-1
#pragma unroll
        for (int s = 0; s < 16; ++s) Sp[s] = 0.f;
        for (int v = 0; v < w; ++v) {  // <=3 iters, wave-uniform
#pragma unroll
            for (int s = 0; s < 16; ++s)
                Sp[s] = W[v][s] + ((s & 1) ? Mf : Ms) * Sp[s];
        }

        // ---- carry-in per chunk, phase 2 (in-place output) ----------------
        float ys[8], yf[8];
#pragma unroll
        for (int f = 0; f < 8; ++f) {
            ys[f] = (l == 0) ? Sp[2*f+0] : qe[2*f+0] + Dls * Sp[2*f+0];
            yf[f] = (l == 0) ? Sp[2*f+1] : qe[2*f+1] + Dlf * Sp[2*f+1];
        }
        if (j == 0) {
#pragma unroll
            for (int f = 0; f < 8; ++f) { ys[f] = cin_s[f]; yf[f] = cin_f[f]; }
        }
#pragma unroll
        for (int t = 0; t < CHUNK; ++t) {
            int slo = (base + 2*t    ) ^ key;
            int shi = (base + 2*t + 1) ^ key;
            float4 lo = buf[slo];
            float4 hi = buf[shi];
            float xx[8] = {lo.x,lo.y,lo.z,lo.w, hi.x,hi.y,hi.z,hi.w};
            float o[8];
#pragma unroll
            for (int f = 0; f < 8; ++f) {
                ys[f] = AS * xx[f] + OMS * ys[f];
                yf[f] = AF * xx[f] + OMF * yf[f];
                o[f]  = ys[f] - yf[f];
            }
            buf[slo] = make_float4(o[0], o[1], o[2], o[3]);
            buf[shi] = make_float4(o[4], o[5], o[6], o[7]);
        }
        // last chunk's end state seeds the next tile
        if (j == NTHR - 1) {
#pragma unroll
            for (int f = 0; f < 8; ++f) { carryS[f] = ys[f]; carryF[f] = yf[f]; }
        }
        __syncthreads();               // outputs + carry visible block-wide

        // ---- copyout: swizzled LDS reads -> coalesced nontemporal stores --
        const f32x4* bufv = (const f32x4*)buf;
#pragma unroll
        for (int k = 0; k < LD_PT; ++k) {
            int g = k * NTHR + j;
            __builtin_nontemporal_store(bufv[swz(g)], &og[g]);
        }
    }
}

extern "C" void kernel_launch(void* const* d_in, const int* in_sizes, int n_in,
                              void* d_out, int out_size, void* d_ws, size_t ws_size,
                              hipStream_t stream) {
    (void)n_in; (void)d_ws; (void)ws_size; (void)out_size;
    const float* x = (const float*)d_in[0];
    float* out = (float*)d_out;
    const int B = in_sizes[0] / (T_LEN * FDIM);   // 4096
    macd_kernel<<<dim3(B), dim3(NTHR), 0, stream>>>(x, out);
}